// Round 13
// baseline (4051.097 us; speedup 1.0000x reference)
//
#include <hip/hip_runtime.h>
#include <cmath>

// GRU: B=32, T=512, E=512, H=1024, fp32.
// Phase 1: xgt[t][gate][j][b] = x @ w_ih^T (transposed store)
// Phase 2 (R12): PAIRED-BLOCK stagger. 512 blocks x 512 threads.
//   Blocks 0-255 process batch half A (b 0-15), blocks 256-511 half B
//   (b 16-31); block i and i+256 co-reside on one CU (round-robin dispatch),
//   so one block's sync-chain stalls are filled by the other's compute --
//   no extra barriers, the CU scheduler does the overlap.
//   Per block (R8-proven mechanics, halved): j-slice [4s,4s+4), 12 w_hh rows
//   in LDS; bgrp(4)x kseg(128x8k); 24 ds_read_b128 of w per thread; 4-stage
//   scatter butterfly -> each lane of wave 0 owns one (j,b) output.
//   ONE __syncthreads per step (red_s parity dbuf). Wave 0: tail + coalesced
//   256B/wave write-through ring store + vmcnt(0) + flag publish + poll of
//   its half's 256 flags; waves 1-7 spin on an LDS ready counter (no L3
//   poll fan-out). Split rings per half (R11 correctness lesson).

namespace {
constexpr int BATCH  = 32;
constexpr int TSTEPS = 512;
constexpr int EDIM   = 512;
constexpr int HDIM   = 1024;
constexpr int GDIM   = 3 * HDIM;
constexpr int SLOTH  = HDIM * 16;     // floats per half-slot (64 KB)

constexpr size_t XG_BYTES    = (size_t)TSTEPS * GDIM * BATCH * 4;  // 192 MiB
constexpr size_t FLAGS_BYTES = 4096;
constexpr size_t SLOTH_BYTES = (size_t)SLOTH * 4;                  // 64 KiB
constexpr size_t HBUF_BYTES  = (size_t)HDIM * BATCH * 4;           // fallback
}

// ---------------- Phase 1: xgt = x @ w_ih^T ----------------
__global__ __launch_bounds__(256)
void xg_gemm_f32(const float* __restrict__ x, const float* __restrict__ w_ih,
                 float* __restrict__ xgt)
{
    __shared__ float a_s[16 * 132];
    __shared__ float b_s[16 * 132];

    const int tid = threadIdx.x;
    const int n0 = blockIdx.x * 128;
    const int m0 = blockIdx.y * 128;
    const int tx = tid & 15;
    const int ty = tid >> 4;

    float acc[8][8];
    #pragma unroll
    for (int i = 0; i < 8; ++i)
        #pragma unroll
        for (int j = 0; j < 8; ++j) acc[i][j] = 0.f;

    const int r_ld = tid >> 2;
    const int kq4  = (tid & 3) * 4;

    for (int kc = 0; kc < EDIM; kc += 16) {
        __syncthreads();
        #pragma unroll
        for (int half = 0; half < 2; ++half) {
            const int r = r_ld + half * 64;
            const int m = m0 + r;
            const int bb = m & 31;
            const int tt = m >> 5;
            float4 av = *(const float4*)&x[((size_t)bb * TSTEPS + tt) * EDIM + kc + kq4];
            a_s[(kq4 + 0) * 132 + r] = av.x;
            a_s[(kq4 + 1) * 132 + r] = av.y;
            a_s[(kq4 + 2) * 132 + r] = av.z;
            a_s[(kq4 + 3) * 132 + r] = av.w;
            const int n = n0 + r;
            float4 bv = *(const float4*)&w_ih[(size_t)n * EDIM + kc + kq4];
            b_s[(kq4 + 0) * 132 + r] = bv.x;
            b_s[(kq4 + 1) * 132 + r] = bv.y;
            b_s[(kq4 + 2) * 132 + r] = bv.z;
            b_s[(kq4 + 3) * 132 + r] = bv.w;
        }
        __syncthreads();
        #pragma unroll
        for (int k = 0; k < 16; ++k) {
            float a_r[8], b_r[8];
            *(float4*)&a_r[0] = *(const float4*)&a_s[k * 132 + ty * 8];
            *(float4*)&a_r[4] = *(const float4*)&a_s[k * 132 + ty * 8 + 4];
            *(float4*)&b_r[0] = *(const float4*)&b_s[k * 132 + tx * 8];
            *(float4*)&b_r[4] = *(const float4*)&b_s[k * 132 + tx * 8 + 4];
            #pragma unroll
            for (int i = 0; i < 8; ++i)
                #pragma unroll
                for (int j = 0; j < 8; ++j)
                    acc[i][j] = fmaf(a_r[i], b_r[j], acc[i][j]);
        }
    }

    const int t  = (m0 >> 5) + (ty >> 2);
    const int b0 = (ty & 3) * 8;
    #pragma unroll
    for (int j = 0; j < 8; ++j) {
        const int g    = n0 + tx * 8 + j;
        const int gate = g >> 10;
        const int jj   = g & 1023;
        float* p = &xgt[(((size_t)t * 3 + gate) * 1024 + jj) * 32 + b0];
        *(float4*)p       = make_float4(acc[0][j], acc[1][j], acc[2][j], acc[3][j]);
        *(float4*)(p + 4) = make_float4(acc[4][j], acc[5][j], acc[6][j], acc[7][j]);
    }
}

// ---------------- Phase 2 (paired-block stagger) ----------------
__global__ __launch_bounds__(512, 4)
void gru_pair(const float* __restrict__ h0, const float* __restrict__ w_hh,
              const float* __restrict__ xgt, float* __restrict__ out,
              float* __restrict__ ringA, float* __restrict__ ringB,
              unsigned* __restrict__ flagsA, unsigned* __restrict__ flagsB,
              int nslot)
{
    __shared__ float w_s[12 * 1032];        // 49.5 KB
    __shared__ float red_s[2][8 * 193];     // 12.4 KB parity dbuf
    __shared__ int ready;

    const int tid  = threadIdx.x;
    const int bid  = blockIdx.x;
    const int half = bid >> 8;              // 0 = A (b 0-15), 1 = B (b 16-31)
    const int sid  = bid & 255;
    const int j0   = sid * 4;
    const int hb   = half * 16;

    float* __restrict__ ring      = half ? ringB : ringA;
    unsigned* __restrict__ flags  = half ? flagsB : flagsA;

    // w rows stored as loaded: w_s row = gate*4 + jl
    for (int i = tid; i < 12 * 256; i += 512) {
        const int row  = i >> 8;
        const int c4   = (i & 255) * 4;
        const int gate = row >> 2;
        const int jl   = row & 3;
        *(float4*)&w_s[row * 1032 + c4] =
            *(const float4*)&w_hh[((size_t)gate * HDIM + j0 + jl) * HDIM + c4];
    }
    if (tid == 0) ready = 0;

    const int wv   = tid >> 6;
    const int lane = tid & 63;

    // tail lane -> (j, b-within-half) from the butterfly-final mapping
    const int t_j = 2 * ((lane >> 2) & 1) + ((lane >> 3) & 1);
    const int t_b = (lane & 3) * 4 + 2 * ((lane >> 4) & 1) + ((lane >> 5) & 1);

    // h0 -> ring slot 0 (coalesced: lane -> j=lane>>4, b=lane&15).
    if (tid < 64) {
        const int ij = tid >> 4, ib = tid & 15;
        __hip_atomic_store(&ring[(j0 + ij) * 16 + ib],
                           h0[(size_t)(hb + ib) * HDIM + j0 + ij],
                           __ATOMIC_RELAXED, __HIP_MEMORY_SCOPE_AGENT);
    }

    float hp = 0.f, xr = 0.f, xz = 0.f, xn = 0.f;
    if (wv == 0) {
        hp = h0[(size_t)(hb + t_b) * HDIM + j0 + t_j];
        const size_t ba = (size_t)(j0 + t_j) * 32 + hb + t_b;
        xr = xgt[ba];
        xz = xgt[ba + 32768];
        xn = xgt[ba + 65536];
    }

    // Entry: drain h0 stores, invalidate stale lines from prior replay, publish.
    __syncthreads();
    if (tid < 64) __builtin_amdgcn_fence(__ATOMIC_ACQUIRE, "agent");
    __syncthreads();
    if (tid == 0)
        __hip_atomic_store(&flags[sid], 1u, __ATOMIC_RELAXED, __HIP_MEMORY_SCOPE_AGENT);

    const int bgrp  = tid & 3;
    const int kseg  = tid >> 2;        // 0..127
    const int b0    = bgrp * 4;
    const int kbase = kseg * 8;
    const int hb2 = (lane >> 2) & 1, hb3 = (lane >> 3) & 1;
    const int hb4 = (lane >> 4) & 1, hb5 = (lane >> 5) & 1;

    int slot = 0;
    int next_fence = nslot;

    for (int t = 0; t < TSTEPS; ++t) {
        const int slot_nx = (slot + 1 == nslot) ? 0 : slot + 1;
        const unsigned tgt = (unsigned)(t + 1);

        // ---- gate: wave 0 polls L3 flags; others spin on LDS (no fabric traffic)
        if (wv == 0) {
            const unsigned* fp = &flags[lane];
            for (;;) {
                unsigned a0 = __hip_atomic_load(fp,       __ATOMIC_RELAXED, __HIP_MEMORY_SCOPE_AGENT);
                unsigned a1 = __hip_atomic_load(fp + 64,  __ATOMIC_RELAXED, __HIP_MEMORY_SCOPE_AGENT);
                unsigned a2 = __hip_atomic_load(fp + 128, __ATOMIC_RELAXED, __HIP_MEMORY_SCOPE_AGENT);
                unsigned a3 = __hip_atomic_load(fp + 192, __ATOMIC_RELAXED, __HIP_MEMORY_SCOPE_AGENT);
                unsigned m01 = a0 < a1 ? a0 : a1;
                unsigned m23 = a2 < a3 ? a2 : a3;
                unsigned mn  = m01 < m23 ? m01 : m23;
                if (__all(mn >= tgt)) break;
                __builtin_amdgcn_s_sleep(1);
            }
            if (lane == 0)
                __hip_atomic_store(&ready, t + 1, __ATOMIC_RELAXED, __HIP_MEMORY_SCOPE_WORKGROUP);
        } else {
            while (__hip_atomic_load(&ready, __ATOMIC_RELAXED, __HIP_MEMORY_SCOPE_WORKGROUP) < t + 1)
                __builtin_amdgcn_s_sleep(1);
        }
        if (t == next_fence) {   // ring-slot reuse boundary (rare / never if nslot=512)
            __builtin_amdgcn_fence(__ATOMIC_ACQUIRE, "agent");
            next_fence += nslot;
        }

        // ---- h loads (normal cached; fresh addresses; L2-shared per XCD)
        const float* sp = ring + (size_t)slot * SLOTH;
        float4 hv[8];
        #pragma unroll
        for (int i = 0; i < 8; ++i)
            hv[i] = *(const float4*)&sp[(kbase + i) * 16 + b0];

        // ---- FMA: acc[r] with r = j*3 + g  (w_s row = g*4 + j)
        float acc[12][4];
        #pragma unroll
        for (int r = 0; r < 12; ++r)
            #pragma unroll
            for (int b = 0; b < 4; ++b) acc[r][b] = 0.f;

        #pragma unroll
        for (int q = 0; q < 2; ++q)
            #pragma unroll
            for (int r = 0; r < 12; ++r) {
                const int wrow = (r % 3) * 4 + (r / 3);
                const float4 w4 = *(const float4*)&w_s[wrow * 1032 + kbase + q * 4];
                const float wq[4] = {w4.x, w4.y, w4.z, w4.w};
                #pragma unroll
                for (int i = 0; i < 4; ++i) {
                    const float4 h4i = hv[q * 4 + i];
                    acc[r][0] = fmaf(wq[i], h4i.x, acc[r][0]);
                    acc[r][1] = fmaf(wq[i], h4i.y, acc[r][1]);
                    acc[r][2] = fmaf(wq[i], h4i.z, acc[r][2]);
                    acc[r][3] = fmaf(wq[i], h4i.w, acc[r][3]);
                }
            }

        // ---- 4-stage scatter butterfly over kseg bits (lane bits 2..5)
        float a6[6][4];
        #pragma unroll
        for (int m = 0; m < 6; ++m)
            #pragma unroll
            for (int b = 0; b < 4; ++b) {
                const float send = hb2 ? acc[m][b] : acc[6 + m][b];
                const float recv = __shfl_xor(send, 4, 64);
                a6[m][b] = (hb2 ? acc[6 + m][b] : acc[m][b]) + recv;
            }
        float a3[3][4];
        #pragma unroll
        for (int m = 0; m < 3; ++m)
            #pragma unroll
            for (int b = 0; b < 4; ++b) {
                const float send = hb3 ? a6[m][b] : a6[3 + m][b];
                const float recv = __shfl_xor(send, 8, 64);
                a3[m][b] = (hb3 ? a6[3 + m][b] : a6[m][b]) + recv;
            }
        float a2[3][2];
        #pragma unroll
        for (int g = 0; g < 3; ++g)
            #pragma unroll
            for (int b = 0; b < 2; ++b) {
                const float send = hb4 ? a3[g][b] : a3[g][2 + b];
                const float recv = __shfl_xor(send, 16, 64);
                a2[g][b] = (hb4 ? a3[g][2 + b] : a3[g][b]) + recv;
            }
        float a1[3];
        #pragma unroll
        for (int g = 0; g < 3; ++g) {
            const float send = hb5 ? a2[g][0] : a2[g][1];
            const float recv = __shfl_xor(send, 32, 64);
            a1[g] = (hb5 ? a2[g][1] : a2[g][0]) + recv;
        }
        {
            float* dst = &red_s[t & 1][wv * 193 + lane * 3];
            dst[0] = a1[0]; dst[1] = a1[1]; dst[2] = a1[2];
        }

        __syncthreads();   // the ONE barrier per step: red_s[t&1] complete

        // ---- tail: wave 0 only; waves 1-7 loop straight to the next spin
        if (wv == 0) {
            const float* rb = red_s[t & 1];
            float s0 = 0.f, s1 = 0.f, s2 = 0.f;
            #pragma unroll
            for (int w = 0; w < 8; ++w) {
                const float* rs = &rb[w * 193 + lane * 3];
                s0 += rs[0]; s1 += rs[1]; s2 += rs[2];
            }
            const float rg   = 1.f / (1.f + expf(-(xr + s0)));
            const float zg   = 1.f / (1.f + expf(-(xz + s1)));
            const float ng   = tanhf(xn + rg * s2);
            const float hnew = (1.f - zg) * ng + zg * hp;
            hp = hnew;

            if (t + 1 < TSTEPS) {
                // coalesced 256B/wave write-through store of h(t+1)
                __hip_atomic_store(&ring[(size_t)slot_nx * SLOTH + (j0 + t_j) * 16 + t_b],
                                   hnew, __ATOMIC_RELAXED, __HIP_MEMORY_SCOPE_AGENT);
                asm volatile("s_waitcnt vmcnt(0)" ::: "memory");
                if (lane == 0)
                    __hip_atomic_store(&flags[sid], (unsigned)(t + 2),
                                       __ATOMIC_RELAXED, __HIP_MEMORY_SCOPE_AGENT);
                // out + next xg prefetch ride behind the publish
                out[((size_t)(hb + t_b) * TSTEPS + t) * HDIM + j0 + t_j] = hnew;
                const size_t b2 = ((size_t)(t + 1) * 3072 + (j0 + t_j)) * 32 + hb + t_b;
                xr = xgt[b2];
                xz = xgt[b2 + 32768];
                xn = xgt[b2 + 65536];
            } else {
                out[((size_t)(hb + t_b) * TSTEPS + t) * HDIM + j0 + t_j] = hnew;
            }
        }

        slot = slot_nx;
    }
}

// ---------------- Phase 2 (fallback, R5 structure, known-correct) ----------------
__global__ __launch_bounds__(1024, 4)
void gru_recurrence(const float* __restrict__ h0, const float* __restrict__ w_hh,
                    const float* __restrict__ xgt, float* __restrict__ out,
                    float* __restrict__ hbufA, float* __restrict__ hbufB,
                    unsigned* __restrict__ flags)
{
    __shared__ float w_s[12 * 1032];
    __shared__ float red_s[16 * 8 * 83];

    const int tid = threadIdx.x;
    const int bid = blockIdx.x;
    const int j0  = bid * 4;

    for (int i = tid; i < 12 * 256; i += 1024) {
        const int row  = i >> 8;
        const int c4   = (i & 255) * 4;
        const int gate = row >> 2;
        const int jl   = row & 3;
        *(float4*)&w_s[row * 1032 + c4] =
            *(const float4*)&w_hh[((size_t)gate * HDIM + j0 + jl) * HDIM + c4];
    }

    const int tjl = tid >> 5;
    const int tb  = tid & 31;

    float hp = 0.f, hnew = 0.f;
    if (tid < 128) {
        hp = h0[(size_t)tb * HDIM + j0 + tjl];
        __hip_atomic_store(&hbufA[(j0 + tjl) * 32 + tb], hp,
                           __ATOMIC_RELAXED, __HIP_MEMORY_SCOPE_AGENT);
    }

    __syncthreads();
    if (tid == 0)
        __hip_atomic_store(&flags[bid * 8], 1u,
                           __ATOMIC_RELAXED, __HIP_MEMORY_SCOPE_AGENT);

    float xr = 0.f, xz = 0.f, xn = 0.f;
    if (tid < 128) {
        const size_t base = (size_t)(j0 + tjl) * 32 + tb;
        xr = xgt[base];
        xz = xgt[base + 32768];
        xn = xgt[base + 65536];
    }
    if (tid < 256) {
        const unsigned* fp = &flags[tid * 8];
        while (__hip_atomic_load(fp, __ATOMIC_RELAXED, __HIP_MEMORY_SCOPE_AGENT) < 1u)
            __builtin_amdgcn_s_sleep(2);
    }
    __syncthreads();

    const int bgrp  = tid & 7;
    const int kseg  = tid >> 3;
    const int b0    = bgrp * 4;
    const int kbase = kseg * 8;
    const int wvi   = tid >> 6;
    const int h3  = (tid >> 3) & 1;
    const int h4b = (tid >> 4) & 1;
    const int h5  = (tid >> 5) & 1;
    const int rbase = 6 * h3 + 3 * h4b;
    const int bb2   = 2 * h5;

    for (int t = 0; t < TSTEPS; ++t) {
        const float* hcur = (t & 1) ? hbufB : hbufA;
        float* hnxt       = (t & 1) ? hbufA : hbufB;

        float4 hv[8];
        #pragma unroll
        for (int i = 0; i < 8; ++i) {
            const float* p = &hcur[(kbase + i) * 32 + b0];
            unsigned long long lo = __hip_atomic_load(
                (const unsigned long long*)p, __ATOMIC_RELAXED, __HIP_MEMORY_SCOPE_AGENT);
            unsigned long long hi = __hip_atomic_load(
                (const unsigned long long*)(p + 2), __ATOMIC_RELAXED, __HIP_MEMORY_SCOPE_AGENT);
            hv[i].x = __uint_as_float((unsigned)lo);
            hv[i].y = __uint_as_float((unsigned)(lo >> 32));
            hv[i].z = __uint_as_float((unsigned)hi);
            hv[i].w = __uint_as_float((unsigned)(hi >> 32));
        }

        float acc[12][4];
        #pragma unroll
        for (int r = 0; r < 12; ++r)
            #pragma unroll
            for (int b = 0; b < 4; ++b) acc[r][b] = 0.f;

        #pragma unroll
        for (int q = 0; q < 2; ++q)
            #pragma unroll
            for (int r = 0; r < 12; ++r) {
                const float4 w4 = *(const float4*)&w_s[r * 1032 + kbase + q * 4];
                const float wq[4] = {w4.x, w4.y, w4.z, w4.w};
                #pragma unroll
                for (int i = 0; i < 4; ++i) {
                    const float4 h4i = hv[q * 4 + i];
                    acc[r][0] = fmaf(wq[i], h4i.x, acc[r][0]);
                    acc[r][1] = fmaf(wq[i], h4i.y, acc[r][1]);
                    acc[r][2] = fmaf(wq[i], h4i.z, acc[r][2]);
                    acc[r][3] = fmaf(wq[i], h4i.w, acc[r][3]);
                }
            }

        float a6[6][4];
        #pragma unroll
        for (int m = 0; m < 6; ++m)
            #pragma unroll
            for (int b = 0; b < 4; ++b) {
                const float send = h3 ? acc[m][b] : acc[6 + m][b];
                const float recv = __shfl_xor(send, 8, 64);
                a6[m][b] = (h3 ? acc[6 + m][b] : acc[m][b]) + recv;
            }
        float a3[3][4];
        #pragma unroll
        for (int m = 0; m < 3; ++m)
            #pragma unroll
            for (int b = 0; b < 4; ++b) {
                const float send = h4b ? a6[m][b] : a6[3 + m][b];
                const float recv = __shfl_xor(send, 16, 64);
                a3[m][b] = (h4b ? a6[3 + m][b] : a6[m][b]) + recv;
            }
        float a2[3][2];
        #pragma unroll
        for (int m = 0; m < 3; ++m)
            #pragma unroll
            for (int b = 0; b < 2; ++b) {
                const float send = h5 ? a3[m][b] : a3[m][2 + b];
                const float recv = __shfl_xor(send, 32, 64);
                a2[m][b] = (h5 ? a3[m][2 + b] : a3[m][b]) + recv;
            }
        {
            float* dst = &red_s[(wvi * 8 + bgrp) * 83];
            #pragma unroll
            for (int m = 0; m < 3; ++m) {
                dst[(rbase + m) * 4 + bb2 + 0] = a2[m][0];
                dst[(rbase + m) * 4 + bb2 + 1] = a2[m][1];
            }
        }
        __syncthreads();

        if (tid < 128) {
            const int bg = tb >> 2, bs = tb & 3;
            float s0 = 0.f, s1 = 0.f, s2 = 0.f;
            #pragma unroll
            for (int w = 0; w < 16; ++w) {
                const float* rs = &red_s[(w * 8 + bg) * 83 + bs];
                s0 += rs[(0 * 4 + tjl) * 4];
                s1 += rs[(1 * 4 + tjl) * 4];
                s2 += rs[(2 * 4 + tjl) * 4];
            }
            const float rg   = 1.f / (1.f + expf(-(xr + s0)));
            const float zg   = 1.f / (1.f + expf(-(xz + s1)));
            const float ng   = tanhf(xn + rg * s2);
            hnew = (1.f - zg) * ng + zg * hp;
            hp = hnew;
            __hip_atomic_store(&hnxt[(j0 + tjl) * 32 + tb], hnew,
                               __ATOMIC_RELAXED, __HIP_MEMORY_SCOPE_AGENT);
        }

        __syncthreads();
        if (tid == 0)
            __hip_atomic_store(&flags[bid * 8], (unsigned)(t + 2),
                               __ATOMIC_RELAXED, __HIP_MEMORY_SCOPE_AGENT);

        if (tid < 128) {
            out[((size_t)tb * TSTEPS + t) * HDIM + j0 + tjl] = hnew;
            if (t + 1 < TSTEPS) {
                const size_t b2 = ((size_t)(t + 1) * 3072 + (j0 + tjl)) * 32 + tb;
                xr = xgt[b2];
                xz = xgt[b2 + 32768];
                xn = xgt[b2 + 65536];
            }
        }

        if (t + 1 < TSTEPS) {
            if (tid < 256) {
                const unsigned* fp = &flags[tid * 8];
                while (__hip_atomic_load(fp, __ATOMIC_RELAXED, __HIP_MEMORY_SCOPE_AGENT)
                       < (unsigned)(t + 2))
                    __builtin_amdgcn_s_sleep(2);
            }
            __syncthreads();
        }
    }
}

extern "C" void kernel_launch(void* const* d_in, const int* in_sizes, int n_in,
                              void* d_out, int out_size, void* d_ws, size_t ws_size,
                              hipStream_t stream)
{
    const float* x    = (const float*)d_in[0];
    const float* h0   = (const float*)d_in[1];
    const float* w_ih = (const float*)d_in[2];
    const float* w_hh = (const float*)d_in[3];
    float* out = (float*)d_out;

    char* ws = (char*)d_ws;
    float* xgt = (float*)ws;

    dim3 g1(GDIM / 128, (BATCH * TSTEPS) / 128);  // 24 x 128
    xg_gemm_f32<<<g1, 256, 0, stream>>>(x, w_ih, xgt);

    // Layout: [xgt 192MiB][flags 4KiB][ringA nslot*64KiB][ringB nslot*64KiB]
    size_t avail = (ws_size > XG_BYTES + FLAGS_BYTES)
                       ? (ws_size - XG_BYTES - FLAGS_BYTES) : 0;
    int nslot = (int)(avail / (2 * SLOTH_BYTES));
    if (nslot > TSTEPS) nslot = TSTEPS;

    if (nslot >= 64) {
        unsigned* flagsA = (unsigned*)(ws + XG_BYTES);
        unsigned* flagsB = flagsA + 256;
        float* ringA     = (float*)(ws + XG_BYTES + FLAGS_BYTES);
        float* ringB     = ringA + (size_t)nslot * SLOTH;
        hipMemsetAsync(flagsA, 0, FLAGS_BYTES, stream);
        gru_pair<<<512, 512, 0, stream>>>(h0, w_hh, xgt, out, ringA, ringB,
                                          flagsA, flagsB, nslot);
    } else {
        float* hbufA    = (float*)(ws + XG_BYTES);
        float* hbufB    = (float*)(ws + XG_BYTES + HBUF_BYTES);
        unsigned* flags = (unsigned*)(ws + XG_BYTES + 2 * HBUF_BYTES);
        hipMemsetAsync(flags, 0, 256 * 8 * sizeof(unsigned), stream);
        gru_recurrence<<<256, 1024, 0, stream>>>(h0, w_hh, xgt, out, hbufA, hbufB, flags);
    }
}

// Round 14
// 3649.929 us; speedup vs baseline: 1.1099x; 1.1099x over previous
//
#include <hip/hip_runtime.h>
#include <cmath>

// GRU: B=32, T=512, E=512, H=1024, fp32.
// Phase 1: xgt[t][gate][j][b] = x @ w_ih^T (transposed store)
// Phase 2 (R13): minimal-chain persistent ring kernel. 256 blocks x 1024 thr.
//   Lesson R9-R12: total = 512 x per-step chain latency, independent of how
//   many parallel streams. So shorten the chain:
//   - ONE __syncthreads/step (red_s parity dbuf). Tail = waves 0-1 only;
//     waves 2-15 fall through to an LDS `ready` spin and start step t+1
//     while wave0 tails/publishes/polls (tail+flag RTT off their path).
//   - Lane-exclusive butterfly (R12 pattern, 0 bank conflicts), red_s
//     stride-7 (bank-clean tail reads).
//   - Publish: tail waves vmcnt(0) -> LDS done-counter -> 1 flag store;
//     wave0 polls 256 packed flags (4/lane), sets LDS ready.
//   - h ring: write-through agent atomics -> L3; consumers NORMAL cached
//     loads (XCD-L2 shared, R8-proven); entry acquire fence + fence at
//     ring-slot reuse (t == multiple of nslot).

namespace {
constexpr int BATCH  = 32;
constexpr int TSTEPS = 512;
constexpr int EDIM   = 512;
constexpr int HDIM   = 1024;
constexpr int GDIM   = 3 * HDIM;
constexpr int SLOT   = HDIM * BATCH;          // 32768 floats = 128 KB

constexpr size_t XG_BYTES    = (size_t)TSTEPS * GDIM * BATCH * 4;  // 192 MiB
constexpr size_t FLAGS_BYTES = 4096;
constexpr size_t SLOT_BYTES  = (size_t)SLOT * 4;
}

// ---------------- Phase 1: xgt = x @ w_ih^T ----------------
__global__ __launch_bounds__(256)
void xg_gemm_f32(const float* __restrict__ x, const float* __restrict__ w_ih,
                 float* __restrict__ xgt)
{
    __shared__ float a_s[16 * 132];
    __shared__ float b_s[16 * 132];

    const int tid = threadIdx.x;
    const int n0 = blockIdx.x * 128;
    const int m0 = blockIdx.y * 128;
    const int tx = tid & 15;
    const int ty = tid >> 4;

    float acc[8][8];
    #pragma unroll
    for (int i = 0; i < 8; ++i)
        #pragma unroll
        for (int j = 0; j < 8; ++j) acc[i][j] = 0.f;

    const int r_ld = tid >> 2;
    const int kq4  = (tid & 3) * 4;

    for (int kc = 0; kc < EDIM; kc += 16) {
        __syncthreads();
        #pragma unroll
        for (int half = 0; half < 2; ++half) {
            const int r = r_ld + half * 64;
            const int m = m0 + r;
            const int bb = m & 31;
            const int tt = m >> 5;
            float4 av = *(const float4*)&x[((size_t)bb * TSTEPS + tt) * EDIM + kc + kq4];
            a_s[(kq4 + 0) * 132 + r] = av.x;
            a_s[(kq4 + 1) * 132 + r] = av.y;
            a_s[(kq4 + 2) * 132 + r] = av.z;
            a_s[(kq4 + 3) * 132 + r] = av.w;
            const int n = n0 + r;
            float4 bv = *(const float4*)&w_ih[(size_t)n * EDIM + kc + kq4];
            b_s[(kq4 + 0) * 132 + r] = bv.x;
            b_s[(kq4 + 1) * 132 + r] = bv.y;
            b_s[(kq4 + 2) * 132 + r] = bv.z;
            b_s[(kq4 + 3) * 132 + r] = bv.w;
        }
        __syncthreads();
        #pragma unroll
        for (int k = 0; k < 16; ++k) {
            float a_r[8], b_r[8];
            *(float4*)&a_r[0] = *(const float4*)&a_s[k * 132 + ty * 8];
            *(float4*)&a_r[4] = *(const float4*)&a_s[k * 132 + ty * 8 + 4];
            *(float4*)&b_r[0] = *(const float4*)&b_s[k * 132 + tx * 8];
            *(float4*)&b_r[4] = *(const float4*)&b_s[k * 132 + tx * 8 + 4];
            #pragma unroll
            for (int i = 0; i < 8; ++i)
                #pragma unroll
                for (int j = 0; j < 8; ++j)
                    acc[i][j] = fmaf(a_r[i], b_r[j], acc[i][j]);
        }
    }

    const int t  = (m0 >> 5) + (ty >> 2);
    const int b0 = (ty & 3) * 8;
    #pragma unroll
    for (int j = 0; j < 8; ++j) {
        const int g    = n0 + tx * 8 + j;
        const int gate = g >> 10;
        const int jj   = g & 1023;
        float* p = &xgt[(((size_t)t * 3 + gate) * 1024 + jj) * 32 + b0];
        *(float4*)p       = make_float4(acc[0][j], acc[1][j], acc[2][j], acc[3][j]);
        *(float4*)(p + 4) = make_float4(acc[4][j], acc[5][j], acc[6][j], acc[7][j]);
    }
}

// ---------------- Phase 2: minimal-chain recurrence ----------------
__global__ __launch_bounds__(1024, 4)
void gru_fast(const float* __restrict__ h0, const float* __restrict__ w_hh,
              const float* __restrict__ xgt, float* __restrict__ out,
              float* __restrict__ ring, unsigned* __restrict__ flags,
              int nslot)
{
    __shared__ float w_s[12 * 1032];          // 49.5 KB
    __shared__ float red_s[2][16 * 449];      // 57.4 KB parity dbuf, stride-7 lanes
    __shared__ int ready;                     // highest step whose inputs are ready
    __shared__ unsigned done;                 // tail-wave publish handshake

    const int tid = threadIdx.x;
    const int bid = blockIdx.x;
    const int j0  = bid * 4;

    // w_s row = gate*4 + jl
    for (int i = tid; i < 12 * 256; i += 1024) {
        const int row = i >> 8;
        const int c4  = (i & 255) * 4;
        *(float4*)&w_s[row * 1032 + c4] =
            *(const float4*)&w_hh[((size_t)(row >> 2) * HDIM + j0 + (row & 3)) * HDIM + c4];
    }
    if (tid == 0) { ready = -1; done = 0u; }

    const int wv   = tid >> 6;
    const int lane = tid & 63;
    const int bgrp = tid & 7;
    const int kseg = tid >> 3;                // 0..127; wave wv owns ksegs [8wv,8wv+8)
    const int b0   = bgrp * 4;
    const int kbase = kseg * 8;
    const int hb3 = (lane >> 3) & 1, hb4 = (lane >> 4) & 1, hb5 = (lane >> 5) & 1;

    // tail identity (tid<128): output (t_j, t_b)
    const int t_j = (tid >> 5) & 3;
    const int t_b = tid & 31;
    const int src_lane = (t_b >> 2) | ((t_j >> 1) << 3) | ((t_j & 1) << 4)
                       | (((t_b >> 1) & 1) << 5);
    const int t_bb = t_b & 1;

    float hp = 0.f, xr = 0.f, xz = 0.f, xn = 0.f;
    if (tid < 128) {
        hp = h0[(size_t)t_b * HDIM + j0 + t_j];
        __hip_atomic_store(&ring[(j0 + t_j) * 32 + t_b], hp,
                           __ATOMIC_RELAXED, __HIP_MEMORY_SCOPE_AGENT);
        const size_t ba = (size_t)(j0 + t_j) * 32 + t_b;
        xr = xgt[ba];
        xz = xgt[ba + 32768];
        xn = xgt[ba + 65536];
    }

    __syncthreads();                           // h0 stores drained; ready/done init
    if (tid < 64) __builtin_amdgcn_fence(__ATOMIC_ACQUIRE, "agent");  // entry inv
    __syncthreads();
    if (tid == 0)
        __hip_atomic_store(&flags[bid], 1u, __ATOMIC_RELAXED, __HIP_MEMORY_SCOPE_AGENT);

    // entry poll (wave0): all blocks published h0
    if (wv == 0) {
        const unsigned* fp = &flags[lane];
        for (;;) {
            unsigned a0 = __hip_atomic_load(fp,       __ATOMIC_RELAXED, __HIP_MEMORY_SCOPE_AGENT);
            unsigned a1 = __hip_atomic_load(fp + 64,  __ATOMIC_RELAXED, __HIP_MEMORY_SCOPE_AGENT);
            unsigned a2 = __hip_atomic_load(fp + 128, __ATOMIC_RELAXED, __HIP_MEMORY_SCOPE_AGENT);
            unsigned a3 = __hip_atomic_load(fp + 192, __ATOMIC_RELAXED, __HIP_MEMORY_SCOPE_AGENT);
            unsigned m01 = a0 < a1 ? a0 : a1;
            unsigned m23 = a2 < a3 ? a2 : a3;
            unsigned mn  = m01 < m23 ? m01 : m23;
            if (__all(mn >= 1u)) break;
            __builtin_amdgcn_s_sleep(1);
        }
        if (lane == 0)
            __hip_atomic_store(&ready, 0, __ATOMIC_RELAXED, __HIP_MEMORY_SCOPE_WORKGROUP);
    }

    int slot = 0;
    int next_fence = nslot;

    for (int t = 0; t < TSTEPS; ++t) {
        const int slot_nx = (slot + 1 == nslot) ? 0 : slot + 1;

        // gate on LDS ready (wave0 set it; cheap local spin for others)
        while (__hip_atomic_load(&ready, __ATOMIC_RELAXED, __HIP_MEMORY_SCOPE_WORKGROUP) < t)
            __builtin_amdgcn_s_sleep(1);
        if (t == next_fence) {                 // ring-slot reuse boundary (rare)
            __builtin_amdgcn_fence(__ATOMIC_ACQUIRE, "agent");
            next_fence += nslot;
        }

        // h loads: normal cached float4 (fresh addresses -> XCD-L2 shared)
        const float* sp = ring + (size_t)slot * SLOT;
        float4 hv[8];
        #pragma unroll
        for (int i = 0; i < 8; ++i)
            hv[i] = *(const float4*)&sp[(kbase + i) * 32 + b0];

        // FMA: acc[r][b], r = j*3 + g  (w_s row = g*4 + j)
        float acc[12][4];
        #pragma unroll
        for (int r = 0; r < 12; ++r)
            #pragma unroll
            for (int b = 0; b < 4; ++b) acc[r][b] = 0.f;

        #pragma unroll
        for (int q = 0; q < 2; ++q)
            #pragma unroll
            for (int r = 0; r < 12; ++r) {
                const int wrow = (r % 3) * 4 + (r / 3);
                const float4 w4 = *(const float4*)&w_s[wrow * 1032 + kbase + q * 4];
                const float wq[4] = {w4.x, w4.y, w4.z, w4.w};
                #pragma unroll
                for (int i = 0; i < 4; ++i) {
                    const float4 h4i = hv[q * 4 + i];
                    acc[r][0] = fmaf(wq[i], h4i.x, acc[r][0]);
                    acc[r][1] = fmaf(wq[i], h4i.y, acc[r][1]);
                    acc[r][2] = fmaf(wq[i], h4i.z, acc[r][2]);
                    acc[r][3] = fmaf(wq[i], h4i.w, acc[r][3]);
                }
            }

        // 3-stage lane-exclusive butterfly over kseg bits (lane bits 3,4,5)
        float a6[6][4];
        #pragma unroll
        for (int m = 0; m < 6; ++m)
            #pragma unroll
            for (int b = 0; b < 4; ++b) {
                const float send = hb3 ? acc[m][b] : acc[6 + m][b];
                const float recv = __shfl_xor(send, 8, 64);
                a6[m][b] = (hb3 ? acc[6 + m][b] : acc[m][b]) + recv;   // j-high = hb3
            }
        float a3[3][4];
        #pragma unroll
        for (int g = 0; g < 3; ++g)
            #pragma unroll
            for (int b = 0; b < 4; ++b) {
                const float send = hb4 ? a6[g][b] : a6[3 + g][b];
                const float recv = __shfl_xor(send, 16, 64);
                a3[g][b] = (hb4 ? a6[3 + g][b] : a6[g][b]) + recv;     // j-low = hb4
            }
        float a2[3][2];
        #pragma unroll
        for (int g = 0; g < 3; ++g)
            #pragma unroll
            for (int b = 0; b < 2; ++b) {
                const float send = hb5 ? a2[g][b] : a3[g][2 + b];      // placeholder fix below
                (void)send;
            }
        // (written explicitly to avoid self-reference)
        #pragma unroll
        for (int g = 0; g < 3; ++g) {
            #pragma unroll
            for (int b = 0; b < 2; ++b) {
                const float send = hb5 ? a3[g][b] : a3[g][2 + b];
                const float recv = __shfl_xor(send, 32, 64);
                a2[g][b] = (hb5 ? a3[g][2 + b] : a3[g][b]) + recv;     // b-pair = hb5
            }
        }
        {
            float* dst = &red_s[t & 1][wv * 449 + lane * 7];
            #pragma unroll
            for (int g = 0; g < 3; ++g) {
                dst[g * 2 + 0] = a2[g][0];
                dst[g * 2 + 1] = a2[g][1];
            }
        }

        __syncthreads();   // the ONE barrier per step

        if (t + 1 < TSTEPS) {
            if (tid < 128) {
                // tail: sum 16 wave-partials, gates, h update
                const float* rb = red_s[t & 1];
                float s0 = 0.f, s1 = 0.f, s2 = 0.f;
                #pragma unroll
                for (int w = 0; w < 16; ++w) {
                    const float* rs = &rb[w * 449 + src_lane * 7 + t_bb];
                    s0 += rs[0];
                    s1 += rs[2];
                    s2 += rs[4];
                }
                const float rg   = 1.f / (1.f + expf(-(xr + s0)));
                const float zg   = 1.f / (1.f + expf(-(xz + s1)));
                const float ng   = tanhf(xn + rg * s2);
                const float hnew = (1.f - zg) * ng + zg * hp;
                hp = hnew;
                __hip_atomic_store(&ring[(size_t)slot_nx * SLOT + (j0 + t_j) * 32 + t_b],
                                   hnew, __ATOMIC_RELAXED, __HIP_MEMORY_SCOPE_AGENT);
                asm volatile("s_waitcnt vmcnt(0)" ::: "memory");       // drain ring store
                if (lane == 0)
                    __hip_atomic_fetch_add(&done, 1u, __ATOMIC_RELAXED,
                                           __HIP_MEMORY_SCOPE_WORKGROUP);
            }
            if (wv == 0) {
                if (lane == 0) {
                    while (__hip_atomic_load(&done, __ATOMIC_RELAXED,
                                             __HIP_MEMORY_SCOPE_WORKGROUP) < 2u * (t + 1))
                        __builtin_amdgcn_s_sleep(0);
                    __hip_atomic_store(&flags[bid], (unsigned)(t + 2),
                                       __ATOMIC_RELAXED, __HIP_MEMORY_SCOPE_AGENT);
                }
                // out store + xg prefetch ride the poll
                out[((size_t)t_b * TSTEPS + t) * HDIM + j0 + t_j] = hp;
                {
                    const size_t b2 = ((size_t)(t + 1) * 3072 + (j0 + t_j)) * 32 + t_b;
                    xr = xgt[b2];
                    xz = xgt[b2 + 32768];
                    xn = xgt[b2 + 65536];
                }
                const unsigned tgt = (unsigned)(t + 2);
                const unsigned* fp = &flags[lane];
                for (;;) {
                    unsigned a0 = __hip_atomic_load(fp,       __ATOMIC_RELAXED, __HIP_MEMORY_SCOPE_AGENT);
                    unsigned a1 = __hip_atomic_load(fp + 64,  __ATOMIC_RELAXED, __HIP_MEMORY_SCOPE_AGENT);
                    unsigned a2p = __hip_atomic_load(fp + 128, __ATOMIC_RELAXED, __HIP_MEMORY_SCOPE_AGENT);
                    unsigned a3p = __hip_atomic_load(fp + 192, __ATOMIC_RELAXED, __HIP_MEMORY_SCOPE_AGENT);
                    unsigned m01 = a0 < a1 ? a0 : a1;
                    unsigned m23 = a2p < a3p ? a2p : a3p;
                    unsigned mn  = m01 < m23 ? m01 : m23;
                    if (__all(mn >= tgt)) break;
                    __builtin_amdgcn_s_sleep(1);
                }
                if (lane == 0)
                    __hip_atomic_store(&ready, t + 1, __ATOMIC_RELAXED,
                                       __HIP_MEMORY_SCOPE_WORKGROUP);
            } else if (wv == 1) {
                out[((size_t)t_b * TSTEPS + t) * HDIM + j0 + t_j] = hp;
                const size_t b2 = ((size_t)(t + 1) * 3072 + (j0 + t_j)) * 32 + t_b;
                xr = xgt[b2];
                xz = xgt[b2 + 32768];
                xn = xgt[b2 + 65536];
            }
            // waves 2-15: straight to next iteration's ready spin
        } else {
            if (tid < 128) {
                const float* rb = red_s[t & 1];
                float s0 = 0.f, s1 = 0.f, s2 = 0.f;
                #pragma unroll
                for (int w = 0; w < 16; ++w) {
                    const float* rs = &rb[w * 449 + src_lane * 7 + t_bb];
                    s0 += rs[0];
                    s1 += rs[2];
                    s2 += rs[4];
                }
                const float rg   = 1.f / (1.f + expf(-(xr + s0)));
                const float zg   = 1.f / (1.f + expf(-(xz + s1)));
                const float ng   = tanhf(xn + rg * s2);
                const float hnew = (1.f - zg) * ng + zg * hp;
                out[((size_t)t_b * TSTEPS + t) * HDIM + j0 + t_j] = hnew;
            }
        }

        slot = slot_nx;
    }
}

extern "C" void kernel_launch(void* const* d_in, const int* in_sizes, int n_in,
                              void* d_out, int out_size, void* d_ws, size_t ws_size,
                              hipStream_t stream)
{
    const float* x    = (const float*)d_in[0];
    const float* h0   = (const float*)d_in[1];
    const float* w_ih = (const float*)d_in[2];
    const float* w_hh = (const float*)d_in[3];
    float* out = (float*)d_out;

    char* ws = (char*)d_ws;
    float* xgt = (float*)ws;

    dim3 g1(GDIM / 128, (BATCH * TSTEPS) / 128);  // 24 x 128
    xg_gemm_f32<<<g1, 256, 0, stream>>>(x, w_ih, xgt);

    // Layout: [xgt 192MiB][flags 4KiB][ring nslot*128KiB]
    size_t avail = (ws_size > XG_BYTES + FLAGS_BYTES)
                       ? (ws_size - XG_BYTES - FLAGS_BYTES) : 0;
    int nslot = (int)(avail / SLOT_BYTES);
    if (nslot > TSTEPS) nslot = TSTEPS;
    if (nslot < 2) nslot = 2;   // ws_size is known ~256MiB; this never triggers

    unsigned* flags = (unsigned*)(ws + XG_BYTES);
    float* ring     = (float*)(ws + XG_BYTES + FLAGS_BYTES);
    hipMemsetAsync(flags, 0, FLAGS_BYTES, stream);
    gru_fast<<<256, 1024, 0, stream>>>(h0, w_hh, xgt, out, ring, flags, nslot);
}